// Round 9
// baseline (534.091 us; speedup 1.0000x reference)
//
#include <hip/hip_runtime.h>

#define NPTS 4096
#define CH 64
#define BATCH 8
#define KNN 20
#define NEG_SLOPE 0.2f
#define EPSV 1e-5f
#define NEG_INF (-3.4e38f)

typedef float v2f __attribute__((ext_vector_type(2)));

// ---------------- K0: xx[b,n] = sum_c x[b,c,n]^2 ----------------
__global__ void k_xx(const float* __restrict__ x, float* __restrict__ xx) {
  int t = blockIdx.x * 256 + threadIdx.x;          // [0, B*N)
  int b = t >> 12, n = t & (NPTS - 1);
  const float* xp = x + ((size_t)b * CH * NPTS) + n;
  float s = 0.f;
#pragma unroll
  for (int c = 0; c < CH; ++c) { float v = xp[(size_t)c * NPTS]; s = fmaf(v, v, s); }
  xx[t] = s;
}

// ---------------- K2: P'[t,o], Q'[t,o] ----------------
__global__ void k_pq(const float* __restrict__ x, const float* __restrict__ W,
                     const float* __restrict__ gamma, const float* __restrict__ beta,
                     const float* __restrict__ rmean, const float* __restrict__ rvar,
                     float* __restrict__ P, float* __restrict__ Q) {
  __shared__ float Ws1[CH * CH];   // [c][o], W1*inv
  __shared__ float Wsd[CH * CH];   // [c][o], (W2-W1)*inv
  int tid = threadIdx.x;
  for (int i = tid; i < CH * CH; i += 256) {
    int o = i & 63, c = i >> 6;
    float s = gamma[o] * rsqrtf(rvar[o] + EPSV);
    float w1 = W[o * 128 + c], w2 = W[o * 128 + 64 + c];
    Ws1[c * 64 + o] = w1 * s;
    Wsd[c * 64 + o] = (w2 - w1) * s;
  }
  __syncthreads();
  int o = tid & 63, ng = tid >> 6;
  float s = gamma[o] * rsqrtf(rvar[o] + EPSV);
  float shift = beta[o] - rmean[o] * s;
  int base = blockIdx.x * 16;
  for (int rp = 0; rp < 4; ++rp) {
    int t = base + rp * 4 + ng;                    // row in [0, B*N)
    int b = t >> 12, n = t & (NPTS - 1);
    const float* xp = x + ((size_t)b * CH * NPTS) + n;
    float accp = 0.f, accq = 0.f;
#pragma unroll 8
    for (int c = 0; c < CH; ++c) {
      float xv = xp[(size_t)c * NPTS];
      accp = fmaf(xv, Ws1[c * 64 + o], accp);
      accq = fmaf(xv, Wsd[c * 64 + o], accq);
    }
    P[(size_t)t * 64 + o] = accp;
    Q[(size_t)t * 64 + o] = accq + shift;
  }
}

// ---------------- K1 helpers ----------------
// packed fp32 fma: element-wise IEEE fma -> bit-identical to scalar chain
__device__ __forceinline__ v2f fma2(float a, v2f b, v2f c) {
#if __has_builtin(__builtin_elementwise_fma)
  v2f av; av.x = a; av.y = a;
  return __builtin_elementwise_fma(av, b, c);
#else
  v2f r; r.x = fmaf(a, b.x, c.x); r.y = fmaf(a, b.y, c.y); return r;
#endif
}

// ballot-gated serial insert with in-loop threshold tightening (R5-R8, passed).
__device__ __forceinline__ void insert_group(float d, int mg, int lane,
                                             float& vr, int& ir, float& th) {
  unsigned long long hit = __ballot(d > th);
  while (hit) {
    int j = __builtin_ctzll(hit);
    hit &= hit - 1;
    float cv = __shfl(d, j);
    int cm = mg + j;
    unsigned long long km = __ballot(vr >= cv);    // existing equals stay above
    int cnt = __popcll(km);
    float sv = __shfl_up(vr, 1);
    int si = __shfl_up(ir, 1);
    if (lane >= cnt) {
      vr = (lane == cnt) ? cv : sv;
      ir = (lane == cnt) ? cm : si;
    }
    th = __shfl(vr, KNN - 1);                      // refreshed 20th-best
    if (hit) hit &= __ballot(d > th);              // prune sub-threshold hits
  }
}

// bitonic seed sort (R5-R8, passed): 64 (d, col=lane) pairs, d desc, ties ->
// lower col. Equals serial insertion into the empty list -> bit-identical.
__device__ __forceinline__ void seed_sort(float d, int lane,
                                          float& vr, int& ir, float& th) {
  float v = d; int ix = lane;
#pragma unroll
  for (int k = 2; k <= 64; k <<= 1) {
#pragma unroll
    for (int j = k >> 1; j > 0; j >>= 1) {
      float pv = __shfl_xor(v, j);
      int   pi = __shfl_xor(ix, j);
      bool lower = (lane & j) == 0;
      bool desc  = (lane & k) == 0;                // block direction
      bool mineBefore = (v > pv) || (v == pv && ix < pi);
      bool keep = (mineBefore == (lower == desc));
      v  = keep ? v  : pv;
      ix = keep ? ix : pi;
    }
  }
  vr = v; ir = ix; th = __shfl(v, KNN - 1);
}

// GEMM (8 rows x 4 cols per thread; lane==col within each 64-group) +
// register-direct selection. A from LDS broadcast (proven); B DIRECT FROM
// GLOBAL: per-lane coalesced dword loads (one 256B line per wave-instr) on
// the VMEM pipe -> the 4 ds_read_b32/c that saturated the LDS pipe are gone,
// along with ALL per-tile staging and barriers. B is L2-resident (1MB/batch;
// XCD swizzle keeps one batch per XCD's 4MB L2).
// Same fma chains, same candidate order -> bit-identical output.
template <bool SEED>
__device__ __forceinline__ void tile_work(const float* __restrict__ bp,
                                          const float* As,
                                          const float* xxb, int m0, int w, int lane,
                                          const float (&xnr)[8],
                                          float (&val)[8], int (&idx)[8],
                                          float (&thd)[8]) {
  float xm[4];
#pragma unroll
  for (int g = 0; g < 4; ++g) xm[g] = xxb[m0 + 64 * g + lane];

  const float* Aw = As + 8 * w;                    // rows 8w..8w+7, LDA=128
  const float* bc = bp + m0;                       // per-lane: col m0+lane

  v2f accA[8], accB[8];
#pragma unroll
  for (int r = 0; r < 8; ++r) {
    accA[r].x = 0.f; accA[r].y = 0.f; accB[r].x = 0.f; accB[r].y = 0.f;
  }

#pragma unroll 4
  for (int c = 0; c < CH; ++c) {
    float4 A0 = *(const float4*)(Aw + c * 128);      // rows 8w..8w+3 (broadcast)
    float4 A1 = *(const float4*)(Aw + c * 128 + 4);  // rows 8w+4..8w+7
    const float* bcc = bc + (size_t)c * NPTS;
    v2f bbA, bbB;
    bbA.x = bcc[0];                                  // col m0+lane
    bbA.y = bcc[64];                                 // col m0+64+lane
    bbB.x = bcc[128];                                // col m0+128+lane
    bbB.y = bcc[192];                                // col m0+192+lane
    accA[0] = fma2(A0.x, bbA, accA[0]);  accB[0] = fma2(A0.x, bbB, accB[0]);
    accA[1] = fma2(A0.y, bbA, accA[1]);  accB[1] = fma2(A0.y, bbB, accB[1]);
    accA[2] = fma2(A0.z, bbA, accA[2]);  accB[2] = fma2(A0.z, bbB, accB[2]);
    accA[3] = fma2(A0.w, bbA, accA[3]);  accB[3] = fma2(A0.w, bbB, accB[3]);
    accA[4] = fma2(A1.x, bbA, accA[4]);  accB[4] = fma2(A1.x, bbB, accB[4]);
    accA[5] = fma2(A1.y, bbA, accA[5]);  accB[5] = fma2(A1.y, bbB, accB[5]);
    accA[6] = fma2(A1.z, bbA, accA[6]);  accB[6] = fma2(A1.z, bbB, accB[6]);
    accA[7] = fma2(A1.w, bbA, accA[7]);  accB[7] = fma2(A1.w, bbB, accB[7]);
  }

#pragma unroll
  for (int r = 0; r < 8; ++r) {
    float d0 = (2.f * accA[r].x - xnr[r]) - xm[0];
    if constexpr (SEED) {
      seed_sort(d0, lane, val[r], idx[r], thd[r]);  // m0==0: col == lane
    } else {
      insert_group(d0, m0, lane, val[r], idx[r], thd[r]);
    }
    float d1 = (2.f * accA[r].y - xnr[r]) - xm[1];
    insert_group(d1, m0 + 64, lane, val[r], idx[r], thd[r]);
    float d2 = (2.f * accB[r].x - xnr[r]) - xm[2];
    insert_group(d2, m0 + 128, lane, val[r], idx[r], thd[r]);
    float d3 = (2.f * accB[r].y - xnr[r]) - xm[3];
    insert_group(d3, m0 + 192, lane, val[r], idx[r], thd[r]);
  }
}

// ---------------- K1: fused distance-GEMM + register-direct top-20 ----------
// 1024 threads = 16 waves = 4 waves/SIMD; wave w owns rows 8w..8w+7;
// 128 rows/block. LDS = As only (32KB). NO B staging, NO per-tile barriers:
// after the single As barrier, waves run completely independently; B comes
// from L2 via coalesced loads. 1D grid 256 with XCD swizzle (b = id&7):
// consecutive blocks round-robin XCDs, so all 32 row-blocks of batch b land
// on XCD b -> 1MB B working set per XCD, L2-resident (heuristic only).
__launch_bounds__(1024, 4)
__global__ void k_knn(const float* __restrict__ x, const float* __restrict__ xx,
                      int* __restrict__ idxout) {
  __shared__ float As[64 * 128];                   // [c][n], LDA=128
  int tid = threadIdx.x;
  int bid = blockIdx.x;
  int b = bid & 7, nb = bid >> 3;                  // XCD-swizzled decode
  int n0 = nb * 128;
  const float* xb = x + (size_t)b * CH * NPTS;
  const float* xxb = xx + b * NPTS;
  int lane = tid & 63;
  int w = tid >> 6;                                // 0..15

  // stage A-tile [c][n]: 8192 floats, 1024 threads x 8 floats
  {
    int c = tid >> 4, n8 = (tid & 15) << 3;
    float4 v0 = *(const float4*)(xb + (size_t)c * NPTS + n0 + n8);
    float4 v1 = *(const float4*)(xb + (size_t)c * NPTS + n0 + n8 + 4);
    *(float4*)(As + c * 128 + n8) = v0;
    *(float4*)(As + c * 128 + n8 + 4) = v1;
  }

  float xnr[8];
#pragma unroll
  for (int r = 0; r < 8; ++r) xnr[r] = xxb[n0 + 8 * w + r];

  float val[8]; int idx[8]; float thd[8];
#pragma unroll
  for (int r = 0; r < 8; ++r) { val[r] = NEG_INF; idx[r] = 0; thd[r] = NEG_INF; }

  __syncthreads();                                 // As ready (the ONLY barrier)

  const float* bp = xb + lane;                     // per-lane B base

  // tile 0: seeded selection
  tile_work<true>(bp, As, xxb, 0, w, lane, xnr, val, idx, thd);

#pragma unroll 1
  for (int mt = 1; mt < NPTS / 256; ++mt)
    tile_work<false>(bp, As, xxb, mt * 256, w, lane, xnr, val, idx, thd);

  // emit: lane l (<20) holds l-th best index for row 8w+r
#pragma unroll
  for (int r = 0; r < 8; ++r) {
    int n = n0 + 8 * w + r;
    if (lane < KNN) idxout[(size_t)(b * NPTS + n) * KNN + lane] = idx[r];
  }
}

// ---------------- K3: gather + max + leaky, transpose to (B,O,N) ----------------
__global__ void k_out(const float* __restrict__ P, const float* __restrict__ Q,
                      const int* __restrict__ idx, float* __restrict__ out) {
  __shared__ float T[64 * 65];
  int tid = threadIdx.x;
  int nb = blockIdx.x, b = blockIdx.y;
  int n0 = nb * 64;
  int o = tid & 63, ng = tid >> 6;
  const float* Pb = P + (size_t)b * NPTS * 64;
  for (int p = 0; p < 16; ++p) {
    int nl = p * 4 + ng;
    int n = n0 + nl;
    const int* ip = idx + (size_t)(b * NPTS + n) * KNN;
    float mx = NEG_INF;
#pragma unroll
    for (int k = 0; k < KNN; ++k) {
      int id = ip[k];
      float v = Pb[(size_t)id * 64 + o];
      mx = fmaxf(mx, v);
    }
    float z = mx + Q[(size_t)(b * NPTS + n) * 64 + o];
    z = (z >= 0.f) ? z : NEG_SLOPE * z;
    T[o * 65 + nl] = z;
  }
  __syncthreads();
  float* ob = out + (size_t)b * 64 * NPTS + n0;
  int nl = tid & 63;
  for (int w = 0; w < 16; ++w) {
    int oo = w * 4 + ng;
    ob[(size_t)oo * NPTS + nl] = T[oo * 65 + nl];
  }
}

extern "C" void kernel_launch(void* const* d_in, const int* in_sizes, int n_in,
                              void* d_out, int out_size, void* d_ws, size_t ws_size,
                              hipStream_t stream) {
  const float* x     = (const float*)d_in[0];
  const float* W     = (const float*)d_in[1];
  const float* gamma = (const float*)d_in[2];
  const float* beta  = (const float*)d_in[3];
  const float* rmean = (const float*)d_in[4];
  const float* rvar  = (const float*)d_in[5];
  float* out = (float*)d_out;

  float* xx = (float*)d_ws;                        // 32768 floats
  float* P  = xx + 32768;                          // 2097152 floats
  float* Q  = P + 2097152;                         // 2097152 floats
  int*   idx = (int*)(Q + 2097152);                // 655360 ints

  k_xx<<<BATCH * NPTS / 256, 256, 0, stream>>>(x, xx);
  k_pq<<<BATCH * NPTS / 16, 256, 0, stream>>>(x, W, gamma, beta, rmean, rvar, P, Q);
  k_knn<<<BATCH * NPTS / 128, 1024, 0, stream>>>(x, xx, idx);
  k_out<<<dim3(NPTS / 64, BATCH), 256, 0, stream>>>(P, Q, idx, out);
}